// Round 1
// baseline (520.587 us; speedup 1.0000x reference)
//
#include <hip/hip_runtime.h>
#include <hip/hip_bf16.h>
#include <cstdint>

// Problem constants
#define BATCH 2048
#define MF    40                 // num fields
#define DDIM  64                 // embedding dim
#define LDIM  128                // hidden size per CIN layer

typedef __attribute__((ext_vector_type(4)))  short    short4_t;
typedef __attribute__((ext_vector_type(8)))  short    short8;
typedef __attribute__((ext_vector_type(8)))  __bf16   bf16x8;
typedef __attribute__((ext_vector_type(2)))  float    floatx2;
typedef __attribute__((ext_vector_type(16))) float    floatx16;

__device__ __forceinline__ unsigned short f32_to_bf16(float f) {
    union { float f; uint32_t u; } v; v.f = f;
    uint32_t u = v.u;
    uint32_t r = (u + 0x7fffu + ((u >> 16) & 1u)) >> 16;   // RNE
    return (unsigned short)r;
}

// raw barrier: execution sync WITHOUT __syncthreads' vmcnt(0)/lgkmcnt(0) drain
__device__ __forceinline__ void barrier_raw() {
    asm volatile("s_barrier" ::: "memory");
}
__device__ __forceinline__ void lgkmwait0() {
    asm volatile("s_waitcnt lgkmcnt(0)" ::: "memory");
}
template <int N> __device__ __forceinline__ void vmwait() {
    if constexpr (N == 0) asm volatile("s_waitcnt vmcnt(0)" ::: "memory");
    if constexpr (N == 2) asm volatile("s_waitcnt vmcnt(2)" ::: "memory");
    if constexpr (N == 3) asm volatile("s_waitcnt vmcnt(3)" ::: "memory");
}

// ---------------------------------------------------------------------------
// W prep, all three layers in ONE launch. Layout UNCHANGED from prior rounds:
//   Wt[m][kk][cb][lane][j] = W[m][ kk*16 + (lane>>5)*8 + j ][ cb*32 + (lane&31) ]
// W0 padded to KK=4 (h in [40,64) -> 0). An 8 KB ring "unit" below is simply
// two consecutive kk-blocks of this array (unit u covers kks {2u,2u+1} of the
// flattened m*KK+kk sequence), so no layout change is needed.
// ---------------------------------------------------------------------------
__global__ void k_wprep_all(const float* __restrict__ W0, const float* __restrict__ W1,
                            const float* __restrict__ W2,
                            unsigned short* __restrict__ W0t,
                            unsigned short* __restrict__ W1t,
                            unsigned short* __restrict__ W2t) {
    int bi = blockIdx.x;                 // W0: 640 blocks, W1/W2: 1280 each
    const float* W; unsigned short* Wt; int KK, H;
    if (bi < 640)       { W = W0; Wt = W0t; KK = 4; H = 40; }
    else if (bi < 1920) { bi -= 640;  W = W1; Wt = W1t; KK = 8; H = 128; }
    else                { bi -= 1920; W = W2; Wt = W2t; KK = 8; H = 128; }
    int lane = threadIdx.x;
    int cb = bi & 3;
    int mkk = bi >> 2;
    int kk = mkk % KK, m = mkk / KK;
    int l = cb * 32 + (lane & 31);
    int hbase = kk * 16 + (lane >> 5) * 8;
    unsigned short o[8];
#pragma unroll
    for (int j = 0; j < 8; ++j) {
        int h = hbase + j;
        float v = (h < H) ? W[((size_t)m * H + h) * LDIM + l] : 0.f;
        o[j] = f32_to_bf16(v);
    }
    *(short8*)(Wt + (((size_t)(m * KK + kk) * 4 + cb) * 64 + lane) * 8) = *(const short8*)o;
}

// ---------------------------------------------------------------------------
// One layer's K-loop, t-split version. Each wave owns ONE d-half (t) and one
// l-half (colhalf): per kk it issues 2 MFMAs (cb pair) with its private
// xk[kk] B-frags in registers. Ring: 8 KB units (2 kk), 4 slots, stage 3
// ahead, barrier per unit, counted gates:
//   per-unit VMEM issues = [s-load if m-top] + 2 global_load_lds
//   gate at unit end: vmcnt(3) on m-top units (don't wait this unit's s),
//   vmcnt(2) otherwise -> stage(u+2) is always drained before unit u+1
//   starts, and unit u+1 (read by unit u's prefetches) was drained one gate
//   earlier. Prologue: stage 0,1,2; vmcnt(2) -> units 0,1 resident.
// ---------------------------------------------------------------------------
template <int KK>
__device__ __forceinline__ void layer_loop(
    const unsigned short* __restrict__ Wt,     // bf16 [MF][KK][4][64][8]
    const float* __restrict__ x, int b, int t,
    int lane, int cbg0, int cbg1,
    unsigned short* slabf,                     // 4 slots x 4096 shorts (8 KB)
    bf16x8 (&xk)[8], floatx16 (&acc)[2])
{
    constexpr int UPM = KK / 2;                // 8 KB units per m
    constexpr int NU  = MF * UPM;              // total units

    auto stage = [&](int uu) {                 // stage unit uu (clamped: same bytes)
        int u = uu < NU ? uu : NU - 1;
        const unsigned short* src = Wt + (size_t)u * 4096;
        const int tid = threadIdx.x;
#pragma unroll
        for (int it = 0; it < 2; ++it) {
            int c = it * 256 + tid;
            __builtin_amdgcn_global_load_lds(
                (const __attribute__((address_space(1))) uint32_t*)(src + (size_t)c * 8),
                (__attribute__((address_space(3))) uint32_t*)(&slabf[(u & 3) * 4096 + c * 8]),
                16, 0, 0);
        }
    };
    auto ldfrag = [&](int u, int f, int cb) {  // f = kk within unit (0/1)
        return __builtin_bit_cast(bf16x8, *(const short8*)(
            &slabf[(u & 3) * 4096 + ((f * 4 + cb) * 64 + lane) * 8]));
    };

    acc[0] = floatx16{}; acc[1] = floatx16{};

    // prologue: fill 3 ring slots; units 0,1 retired before priming
    vmwait<0>();
    stage(0); stage(1); stage(2);
    vmwait<2>();
    barrier_raw();

    bf16x8 bbuf[2][2];                         // W A-frag register ring (2-deep)
#pragma unroll
    for (int p = 0; p < 2; ++p) {
        bbuf[p][0] = ldfrag(0, p, cbg0);
        bbuf[p][1] = ldfrag(0, p, cbg1);
    }

    float sv = 0.f;

#pragma unroll 1
    for (int m = 0; m < MF; ++m) {
        floatx16 P[2] = {};
#pragma unroll
        for (int kk = 0; kk < KK; ++kk) {
            if ((kk & 1) == 0) {               // unit top
                barrier_raw();
                asm volatile("s_setprio 1");
                if (kk == 0)                   // 1 per-lane scalar scale load
                    sv = x[((size_t)b * MF + m) * DDIM + t * 32 + (lane & 31)];
                stage(m * UPM + (kk >> 1) + 3);// 3 units ahead in the ring
            }
            const int slot = kk & 1;
            P[0] = __builtin_amdgcn_mfma_f32_32x32x16_bf16(bbuf[slot][0], xk[kk], P[0], 0, 0, 0);
            P[1] = __builtin_amdgcn_mfma_f32_32x32x16_bf16(bbuf[slot][1], xk[kk], P[1], 0, 0, 0);
            {   // prefetch 2 kk ahead (crosses unit/m boundary; all compile-time)
                const int j  = kk + 2;
                int mm = m + ((j >= KK) ? 1 : 0);
                if (mm > MF - 1) mm = MF - 1;
                const int jj = (j >= KK) ? (j - KK) : j;
                const int u  = mm * UPM + (jj >> 1);
                bbuf[slot][0] = ldfrag(u, jj & 1, cbg0);
                bbuf[slot][1] = ldfrag(u, jj & 1, cbg1);
            }
            if ((kk & 1) == 1) {               // unit-end gate (counted, never 0)
                if (kk == 1) vmwait<3>(); else vmwait<2>();
            }
        }
        asm volatile("s_setprio 0");
        // epilogue: acc += s_t * P (float2 -> v_pk_fma_f32)
#pragma unroll
        for (int cbp = 0; cbp < 2; ++cbp) {
            floatx2 s2 = {sv, sv};
            floatx2*       A = (floatx2*)&acc[cbp];
            const floatx2* Q = (const floatx2*)&P[cbp];
#pragma unroll
            for (int i = 0; i < 8; ++i) A[i] += s2 * Q[i];
        }
    }
}

// ---------------------------------------------------------------------------
// Fused 3-layer CIN kernel, t-split for occupancy. Block = 256 thr = 4 waves,
// ONE batch per block, wave = (t = d-half, c = l-half); each wave computes
// 64 l x 32 d. Per-wave regs ~halve vs the old (rowhalf,colhalf) scheme
// (acc 32 + P 32 + xk 32 + bbuf 16), so __launch_bounds__(256,4) holds
// 4 waves/SIMD = 4 independent blocks/CU (old: 2/SIMD, 2 lockstep blocks).
// LDS 33 KB: 4 x 8 KB W-ring (slots 0-1 double as the 16 KB X-exchange)
// + 1 KB cross-t ps scratch. Grid 2048 = exactly 2 packed rounds at 4/CU.
// ---------------------------------------------------------------------------
__global__ __launch_bounds__(256, 4) void k_cin(
    const float* __restrict__ x,               // fp32 [B][MF][DDIM]
    const unsigned short* __restrict__ W0t,    // bf16 [MF][4][4][64][8] (padded)
    const unsigned short* __restrict__ W1t,    // bf16 [MF][8][4][64][8]
    const unsigned short* __restrict__ W2t,    // bf16 [MF][8][4][64][8]
    float* __restrict__ out)                   // fp32 [B][384]
{
    __shared__ unsigned short slab[4][4096];   // 4 x 8 KB W-ring; slots 0-1
                                               // double as the 16 KB X-exchange
    __shared__ float pscr[2][128];             // cross-t ps reduction scratch
    unsigned short* slabf = &slab[0][0];

    const int tid  = threadIdx.x;
    const int lane = tid & 63, wave = tid >> 6;
    const int hf   = lane >> 5, r31 = lane & 31;
    const int t = wave >> 1, c = wave & 1;     // d-half, l-half
    const int b = blockIdx.x;                  // this block's batch
    const int cbg0 = c * 2, cbg1 = c * 2 + 1;

    bf16x8   xk[8];                            // B-operand fragments (this t)
    floatx16 acc[2];                           // [cbp], D[l, d=t*32+r31]

    // ---- ps: out[b][OFF+l] = sum over all 64 d. Butterfly gives this wave's
    // 32-d partial; cross-t combine through 1 KB LDS scratch. ----
    auto write_ps = [&](int OFF) {
#pragma unroll
        for (int cbp = 0; cbp < 2; ++cbp) {
#pragma unroll
            for (int j = 0; j < 16; ++j) {
                float v = acc[cbp][j];
                v += __shfl_xor(v, 16);
                v += __shfl_xor(v, 8);
                v += __shfl_xor(v, 4);
                v += __shfl_xor(v, 2);
                v += __shfl_xor(v, 1);
                if (r31 == 0)
                    pscr[t][(c * 2 + cbp) * 32 + (j & 3) + 8 * (j >> 2) + 4 * hf] = v;
            }
        }
        lgkmwait0();                           // pscr writes committed
        barrier_raw();
        if (tid < 128)
            out[(size_t)b * 384 + OFF + tid] = pscr[0][tid] + pscr[1][tid];
    };

    // ---- layer boundary: acc -> LDS (reader frag order) -> xk ----
    // Writer element: d = t*32+r31, l = c*64 + cbp*32 + 8g + 4hf + i
    //   => kk = c*4 + cbp*2 + (g>>1), hfr = g&1, j' = 4hf+i, region t.
    auto exchange = [&]() {
        vmwait<0>();                           // drain ring staging + ps stores
        barrier_raw();
#pragma unroll
        for (int cbp = 0; cbp < 2; ++cbp)
#pragma unroll
            for (int g = 0; g < 4; ++g) {
                unsigned short o[4];
#pragma unroll
                for (int i = 0; i < 4; ++i) o[i] = f32_to_bf16(acc[cbp][g * 4 + i]);
                const int kk  = c * 4 + cbp * 2 + (g >> 1);
                const int hfr = g & 1;
                *(short4_t*)(&slabf[((t * 8 + kk) * 64 + hfr * 32 + r31) * 8 + 4 * hf]) =
                    *(const short4_t*)o;
            }
        lgkmwait0();                           // writes committed to LDS
        barrier_raw();
#pragma unroll
        for (int kk = 0; kk < 8; ++kk)
            xk[kk] = __builtin_bit_cast(bf16x8, *(const short8*)(
                &slabf[((t * 8 + kk) * 64 + lane) * 8]));
        lgkmwait0();                           // reads in regs before restaging
        barrier_raw();
    };

    // ---- layer 0: xk from original x (KK=4 padded, h<MF else 0) ----
#pragma unroll
    for (int kk = 0; kk < 4; ++kk) {
        unsigned short tmp[8];
#pragma unroll
        for (int j = 0; j < 8; ++j) {
            int h = kk * 16 + hf * 8 + j;
            float v = (h < MF) ? x[((size_t)b * MF + h) * DDIM + t * 32 + r31] : 0.f;
            tmp[j] = f32_to_bf16(v);
        }
        xk[kk] = __builtin_bit_cast(bf16x8, *(const short8*)tmp);
    }

    layer_loop<4>(W0t, x, b, t, lane, cbg0, cbg1, slabf, xk, acc);
    write_ps(0);
    exchange();

    layer_loop<8>(W1t, x, b, t, lane, cbg0, cbg1, slabf, xk, acc);
    write_ps(128);
    exchange();

    layer_loop<8>(W2t, x, b, t, lane, cbg0, cbg1, slabf, xk, acc);
    write_ps(256);
}

// ---------------------------------------------------------------------------
extern "C" void kernel_launch(void* const* d_in, const int* in_sizes, int n_in,
                              void* d_out, int out_size, void* d_ws, size_t ws_size,
                              hipStream_t stream) {
    const float* x  = (const float*)d_in[0];
    const float* W0 = (const float*)d_in[1];
    const float* W1 = (const float*)d_in[2];
    const float* W2 = (const float*)d_in[3];
    float* out = (float*)d_out;

    char* ws = (char*)d_ws;
    size_t off = 0;
    auto alloc = [&](size_t bytes) -> void* {
        void* p = ws + off;
        off += (bytes + 255) & ~(size_t)255;
        return p;
    };
    unsigned short* W0t = (unsigned short*)alloc((size_t)MF * 4 * 2048 * 2);   // 0.66 MB
    unsigned short* W1t = (unsigned short*)alloc((size_t)MF * 8 * 2048 * 2);   // 1.31 MB
    unsigned short* W2t = (unsigned short*)alloc((size_t)MF * 8 * 2048 * 2);   // 1.31 MB

    k_wprep_all<<<3200, 64, 0, stream>>>(W0, W1, W2, W0t, W1t, W2t);
    k_cin<<<BATCH, 256, 0, stream>>>(x, W0t, W1t, W2t, out);
}

// Round 2
// 451.944 us; speedup vs baseline: 1.1519x; 1.1519x over previous
//
#include <hip/hip_runtime.h>
#include <hip/hip_bf16.h>
#include <cstdint>

// Problem constants
#define BATCH 2048
#define MF    40                 // num fields
#define DDIM  64                 // embedding dim
#define LDIM  128                // hidden size per CIN layer
#define ROWS  (BATCH * DDIM)     // 131072 (b,d) rows

typedef __attribute__((ext_vector_type(4)))  short    short4_t;
typedef __attribute__((ext_vector_type(8)))  short    short8;
typedef __attribute__((ext_vector_type(8)))  __bf16   bf16x8;
typedef __attribute__((ext_vector_type(2)))  float    floatx2;
typedef __attribute__((ext_vector_type(16))) float    floatx16;

// R1 POST-MORTEM (do not revisit):
//  - t-split (1 batch/block, acc[2], 4 blocks/CU) REGRESSED 380->470 us.
//    Matrix-pipe busy time is invariant (~207 us); t-split doubled LDS
//    traffic to ~57 TB/s (near 69 ceiling), quadrupled barriers/MFMA, and
//    spilled under the 128-reg cap (WRITE_SIZE 3->35 MB scratch).
//  - Occupancy is NOT the lever here; the per-CU matrix pipe is shared.

__device__ __forceinline__ unsigned short f32_to_bf16(float f) {
    union { float f; uint32_t u; } v; v.f = f;
    uint32_t u = v.u;
    uint32_t r = (u + 0x7fffu + ((u >> 16) & 1u)) >> 16;   // RNE
    return (unsigned short)r;
}

// raw barrier: execution sync WITHOUT __syncthreads' vmcnt(0)/lgkmcnt(0) drain
__device__ __forceinline__ void barrier_raw() {
    asm volatile("s_barrier" ::: "memory");
}
__device__ __forceinline__ void lgkmwait0() {
    asm volatile("s_waitcnt lgkmcnt(0)" ::: "memory");
}
template <int N> __device__ __forceinline__ void vmwait() {
    if constexpr (N == 0)  asm volatile("s_waitcnt vmcnt(0)"  ::: "memory");
    if constexpr (N == 4)  asm volatile("s_waitcnt vmcnt(4)"  ::: "memory");
    if constexpr (N == 6)  asm volatile("s_waitcnt vmcnt(6)"  ::: "memory");
    if constexpr (N == 10) asm volatile("s_waitcnt vmcnt(10)" ::: "memory");
}

// ---------------------------------------------------------------------------
// W prep, all three layers in ONE launch (saves 2 launch gaps).
//   Wt[m][kk][cb][lane][j] = W[m][ kk*16 + (lane>>5)*8 + j ][ cb*32 + (lane&31) ]
// W0 is padded to KK=4 (h in [40,64) -> 0): zero MFMA terms are exact, and
// the K-loop/ring becomes uniform (KU=4 units everywhere).
// fp32 W reads are NON-TEMPORAL: they're dead after this kernel and must not
// evict the Wt stores (which k_cin streams from L2) or x.
// ---------------------------------------------------------------------------
__global__ void k_wprep_all(const float* __restrict__ W0, const float* __restrict__ W1,
                            const float* __restrict__ W2,
                            unsigned short* __restrict__ W0t,
                            unsigned short* __restrict__ W1t,
                            unsigned short* __restrict__ W2t) {
    int bi = blockIdx.x;                 // W0: 640 blocks, W1/W2: 1280 each
    const float* W; unsigned short* Wt; int KK, H;
    if (bi < 640)       { W = W0; Wt = W0t; KK = 4; H = 40; }
    else if (bi < 1920) { bi -= 640;  W = W1; Wt = W1t; KK = 8; H = 128; }
    else                { bi -= 1920; W = W2; Wt = W2t; KK = 8; H = 128; }
    int lane = threadIdx.x;
    int cb = bi & 3;
    int mkk = bi >> 2;
    int kk = mkk % KK, m = mkk / KK;
    int l = cb * 32 + (lane & 31);
    int hbase = kk * 16 + (lane >> 5) * 8;
    unsigned short o[8];
#pragma unroll
    for (int j = 0; j < 8; ++j) {
        int h = hbase + j;
        float v = (h < H) ? __builtin_nontemporal_load(&W[((size_t)m * H + h) * LDIM + l]) : 0.f;
        o[j] = f32_to_bf16(v);
    }
    *(short8*)(Wt + (((size_t)(m * KK + kk) * 4 + cb) * 64 + lane) * 8) = *(const short8*)o;
}

// ---------------------------------------------------------------------------
// One layer's K-loop: R10's proven ring-4 / raw-barrier / counted-vmcnt body.
// Operand-swapped: W = A-operand, XK = B-operand -> D[l, row]; per-row scale
// s_m is a per-lane scalar applied in a tiny float2 epilogue.
// KK=4 (L0, UPM=1, gate 6) or KK=8 (L1/L2, UPM=2, gate 10).
//
// R2 change: the 2 per-lane scale loads are PREFETCHED ONE FULL m AHEAD
// (s*n -> s*v register ring). Issue count per m-top is unchanged (2), so the
// proven gate arithmetic is untouched; the epilogue's consumer-side margin
// grows from ~1 unit interval to ~2+ (covers HBM-miss latency on x).
// x loads are non-temporal: x is streamed once per layer and was evicting W
// from the 4 MB/XCD L2 (FETCH_SIZE showed ~11 MB of W re-fetch from HBM).
// ---------------------------------------------------------------------------
template <int KK>
__device__ __forceinline__ void layer_loop(
    const unsigned short* __restrict__ Wt,     // bf16 [MF][KK][4][64][8]
    const float* __restrict__ x, int b,
    int lane, int hf, int r31, int cbg0, int cbg1,
    unsigned short* slabf,                     // &slab[0][0]: 4 slots x 8192 shorts
    bf16x8 (&xk)[2][8], floatx16 (&acc)[2][2])
{
    constexpr int UPM  = KK / 4;               // units per m
    constexpr int NU   = MF * UPM;             // total units (16 KB each)
    constexpr int GATE = (KK == 8) ? 10 : 6;   // = vmem insts per m (uniform)

    auto stage = [&](int uu) {                 // stage unit uu (clamped: same bytes)
        int u = uu < NU ? uu : NU - 1;
        const unsigned short* src = Wt + (size_t)u * 8192;
        const int tid = threadIdx.x;
#pragma unroll
        for (int it = 0; it < 4; ++it) {
            int c = it * 256 + tid;
            __builtin_amdgcn_global_load_lds(
                (const __attribute__((address_space(1))) uint32_t*)(src + (size_t)c * 8),
                (__attribute__((address_space(3))) uint32_t*)(&slabf[(size_t)(u & 3) * 8192 + (size_t)c * 8]),
                16, 0, 0);
        }
    };
    auto ldfrag = [&](int u, int frag, int cb) {
        return __builtin_bit_cast(bf16x8, *(const short8*)(
            &slabf[(size_t)(u & 3) * 8192 + ((size_t)(frag * 4 + cb) * 64 + lane) * 8]));
    };

    acc[0][0] = floatx16{}; acc[0][1] = floatx16{};
    acc[1][0] = floatx16{}; acc[1][1] = floatx16{};

    // prologue: fill 3 ring slots; units 0,1 retired before priming.
    // m=0's scale loads are issued FIRST (after the drain) so the vmwait<4>
    // retires them along with stage(0)/stage(1): s*n valid before the loop.
    vmwait<0>();
    float s0n, s1n;
    {
        const float* sp = x + ((size_t)b * MF + 0) * DDIM + r31;
        s0n = __builtin_nontemporal_load(sp);
        s1n = __builtin_nontemporal_load(sp + 32);
    }
    stage(0); stage(1); stage(2);
    vmwait<4>();
    barrier_raw();

    bf16x8 bbuf[2][2];                         // W A-frag register ring
#pragma unroll
    for (int p = 0; p < 2; ++p) {
        bbuf[p][0] = ldfrag(0, p, cbg0);
        bbuf[p][1] = ldfrag(0, p, cbg1);
    }

    float s0v = 0.f, s1v = 0.f;

#pragma unroll 1
    for (int m = 0; m < MF; ++m) {
        floatx16 P[2][2] = {};
#pragma unroll
        for (int kk = 0; kk < KK; ++kk) {
            if (kk % 4 == 0) {                 // unit top
                barrier_raw();
                asm volatile("s_setprio 1");
                if (kk == 0) {                 // rotate scale ring; prefetch m+1
                    s0v = s0n; s1v = s1n;
                    const int mn = (m + 1 < MF) ? m + 1 : MF - 1;   // clamped dead load
                    const float* sp = x + ((size_t)b * MF + mn) * DDIM + r31;
                    s0n = __builtin_nontemporal_load(sp);
                    s1n = __builtin_nontemporal_load(sp + 32);
                }
                stage(m * UPM + kk / 4 + 3);   // 3 units ahead in the ring
            }
            const int slot = kk & 1;
            P[0][0] = __builtin_amdgcn_mfma_f32_32x32x16_bf16(bbuf[slot][0], xk[0][kk], P[0][0], 0, 0, 0);
            P[1][0] = __builtin_amdgcn_mfma_f32_32x32x16_bf16(bbuf[slot][0], xk[1][kk], P[1][0], 0, 0, 0);
            P[0][1] = __builtin_amdgcn_mfma_f32_32x32x16_bf16(bbuf[slot][1], xk[0][kk], P[0][1], 0, 0, 0);
            P[1][1] = __builtin_amdgcn_mfma_f32_32x32x16_bf16(bbuf[slot][1], xk[1][kk], P[1][1], 0, 0, 0);
            {   // prefetch 2 kk ahead (crosses unit/m boundary; all compile-time)
                const int j  = kk + 2;
                int mm = m + ((j >= KK) ? 1 : 0);
                if (mm > MF - 1) mm = MF - 1;
                const int jj = (j >= KK) ? (j - KK) : j;
                const int u  = mm * UPM + jj / 4;
                bbuf[slot][0] = ldfrag(u, jj % 4, cbg0);
                bbuf[slot][1] = ldfrag(u, jj % 4, cbg1);
            }
            if (kk % 4 == 3) vmwait<GATE>();   // uniform end-of-unit gate
        }
        asm volatile("s_setprio 0");
        // epilogue: acc += s_t * P (float2 -> v_pk_fma_f32); s*v arrived >=1
        // full m earlier, so no vmcnt stall here.
#pragma unroll
        for (int t = 0; t < 2; ++t) {
            const float sv = (t == 0) ? s0v : s1v;
            floatx2 s2 = {sv, sv};
#pragma unroll
            for (int cbp = 0; cbp < 2; ++cbp) {
                floatx2*       A = (floatx2*)&acc[t][cbp];
                const floatx2* Q = (const floatx2*)&P[t][cbp];
#pragma unroll
                for (int i = 0; i < 8; ++i) A[i] += s2 * Q[i];
            }
        }
    }
}

// ---------------------------------------------------------------------------
// Fused 3-layer CIN kernel. Block = 256 thr = 4 waves (2x2), 2 batches x all
// 128 l's per block; grid 1024 = 2 blocks/CU. X intermediates NEVER touch
// global: at each layer boundary, waves write their D-layout acc into LDS
// (overlaying ring slots 0-1) in exact reader B-fragment order, then reload
// xk fragments. ps outputs fused per layer (butterfly shuffle).
// NOTE: (256,2) -> 256 unified regs/wave. (512,4) spilled catastrophically
// in round 3 — do not revisit. (256,4) t-split spilled + LDS-BW-bound in R1.
// ---------------------------------------------------------------------------
__global__ __launch_bounds__(256, 2) void k_cin(
    const float* __restrict__ x,               // fp32 [B][MF][DDIM]
    const unsigned short* __restrict__ W0t,    // bf16 [MF][4][4][64][8] (padded)
    const unsigned short* __restrict__ W1t,    // bf16 [MF][8][4][64][8]
    const unsigned short* __restrict__ W2t,    // bf16 [MF][8][4][64][8]
    float* __restrict__ out)                   // fp32 [B][384]
{
    __shared__ unsigned short slab[4][8192];   // 4 x 16 KB W-ring; slots 0-1
                                               // double as the 32 KB X-exchange
    unsigned short* slabf = &slab[0][0];

    const int tid  = threadIdx.x;
    const int lane = tid & 63, wave = tid >> 6;
    const int hf   = lane >> 5, r31 = lane & 31;
    const int rowhalf = wave >> 1, colhalf = wave & 1;
    const int b = blockIdx.x * 2 + rowhalf;    // this wave's batch
    const int cbg0 = colhalf * 2, cbg1 = colhalf * 2 + 1;

    bf16x8   xk[2][8];                         // B-operand fragments
    floatx16 acc[2][2];                        // [t(row-tile)][cbp], D[l,row]

    // ---- ps: out[b][OFF+l] = sum over all 64 d (butterfly across lanes) ----
    // out stores are non-temporal: written once, never read by this kernel.
    auto write_ps = [&](int OFF) {
#pragma unroll
        for (int cbp = 0; cbp < 2; ++cbp) {
#pragma unroll
            for (int j = 0; j < 16; ++j) {
                float v = acc[0][cbp][j] + acc[1][cbp][j];
                v += __shfl_xor(v, 16);
                v += __shfl_xor(v, 8);
                v += __shfl_xor(v, 4);
                v += __shfl_xor(v, 2);
                v += __shfl_xor(v, 1);
                if (r31 == 0)
                    __builtin_nontemporal_store(v,
                        &out[(size_t)b * 384 + OFF + (colhalf * 2 + cbp) * 32 +
                             (j & 3) + 8 * (j >> 2) + 4 * hf]);
            }
        }
    };

    // ---- layer boundary: acc -> LDS (reader frag order) -> xk ----
    // Writer element: row = t*32+r31, l = colhalf*64 + cbp*32 + 8g + 4hf + i
    //   => kk = colhalf*4 + cbp*2 + (g>>1), hfr = g&1, j = 4hf+i
    // Xf addr (shorts): rowhalf*8192 + ((t*8+kk)*64 + hfr*32 + r31)*8 + 4hf
    auto exchange = [&]() {
        vmwait<0>();                           // drain ring staging + ps stores
        barrier_raw();
#pragma unroll
        for (int t = 0; t < 2; ++t)
#pragma unroll
            for (int cbp = 0; cbp < 2; ++cbp)
#pragma unroll
                for (int g = 0; g < 4; ++g) {
                    unsigned short o[4];
#pragma unroll
                    for (int i = 0; i < 4; ++i) o[i] = f32_to_bf16(acc[t][cbp][g * 4 + i]);
                    const int kk  = colhalf * 4 + cbp * 2 + (g >> 1);
                    const int hfr = g & 1;
                    *(short4_t*)(&slabf[(size_t)rowhalf * 8192 +
                        ((size_t)(t * 8 + kk) * 64 + hfr * 32 + r31) * 8 + 4 * hf]) =
                        *(const short4_t*)o;
                }
        lgkmwait0();                           // writes committed to LDS
        barrier_raw();
#pragma unroll
        for (int t = 0; t < 2; ++t)
#pragma unroll
            for (int kk = 0; kk < 8; ++kk)
                xk[t][kk] = __builtin_bit_cast(bf16x8, *(const short8*)(
                    &slabf[(size_t)rowhalf * 8192 + ((size_t)(t * 8 + kk) * 64 + lane) * 8]));
        lgkmwait0();                           // reads in regs before restaging
        barrier_raw();
    };

    // ---- layer 0: xk from original x (KK=4 padded, h<MF else 0) ----
#pragma unroll
    for (int t = 0; t < 2; ++t)
#pragma unroll
        for (int kk = 0; kk < 4; ++kk) {
            unsigned short tmp[8];
#pragma unroll
            for (int j = 0; j < 8; ++j) {
                int h = kk * 16 + hf * 8 + j;
                float v = (h < MF)
                    ? __builtin_nontemporal_load(&x[((size_t)b * MF + h) * DDIM + t * 32 + r31])
                    : 0.f;
                tmp[j] = f32_to_bf16(v);
            }
            xk[t][kk] = __builtin_bit_cast(bf16x8, *(const short8*)tmp);
        }

    layer_loop<4>(W0t, x, b, lane, hf, r31, cbg0, cbg1, slabf, xk, acc);
    write_ps(0);
    exchange();

    layer_loop<8>(W1t, x, b, lane, hf, r31, cbg0, cbg1, slabf, xk, acc);
    write_ps(128);
    exchange();

    layer_loop<8>(W2t, x, b, lane, hf, r31, cbg0, cbg1, slabf, xk, acc);
    write_ps(256);
}

// ---------------------------------------------------------------------------
extern "C" void kernel_launch(void* const* d_in, const int* in_sizes, int n_in,
                              void* d_out, int out_size, void* d_ws, size_t ws_size,
                              hipStream_t stream) {
    const float* x  = (const float*)d_in[0];
    const float* W0 = (const float*)d_in[1];
    const float* W1 = (const float*)d_in[2];
    const float* W2 = (const float*)d_in[3];
    float* out = (float*)d_out;

    char* ws = (char*)d_ws;
    size_t off = 0;
    auto alloc = [&](size_t bytes) -> void* {
        void* p = ws + off;
        off += (bytes + 255) & ~(size_t)255;
        return p;
    };
    unsigned short* W0t = (unsigned short*)alloc((size_t)MF * 4 * 2048 * 2);   // 0.66 MB
    unsigned short* W1t = (unsigned short*)alloc((size_t)MF * 8 * 2048 * 2);   // 1.31 MB
    unsigned short* W2t = (unsigned short*)alloc((size_t)MF * 8 * 2048 * 2);   // 1.31 MB

    k_wprep_all<<<3200, 64, 0, stream>>>(W0, W1, W2, W0t, W1t, W2t);
    k_cin<<<ROWS / 128, 256, 0, stream>>>(x, W0t, W1t, W2t, out);
}

// Round 3
// 434.302 us; speedup vs baseline: 1.1987x; 1.0406x over previous
//
#include <hip/hip_runtime.h>
#include <hip/hip_bf16.h>
#include <cstdint>

// Problem constants
#define BATCH 2048
#define MF    40                 // num fields
#define DDIM  64                 // embedding dim
#define LDIM  128                // hidden size per CIN layer
#define ROWS  (BATCH * DDIM)     // 131072 (b,d) rows

typedef __attribute__((ext_vector_type(4)))  short    short4_t;
typedef __attribute__((ext_vector_type(8)))  short    short8;
typedef __attribute__((ext_vector_type(8)))  __bf16   bf16x8;
typedef __attribute__((ext_vector_type(2)))  float    floatx2;
typedef __attribute__((ext_vector_type(16))) float    floatx16;

// POST-MORTEM LEDGER (do not revisit):
//  R1: t-split 4-blocks/CU REGRESSED 380->470. Matrix busy invariant; LDS
//      traffic doubled (~57 TB/s), barriers/MFMA x4, spilled at 128-reg cap.
//      Occupancy is NOT the lever; the per-CU matrix pipe is shared.
//  R2: nontemporal hints REGRESSED 380->397. NT out-stores are scattered
//      dwords -> partial-line HBM writes, WRITE_SIZE 3->30 MB. NT x-loads
//      raised FETCH (x is re-read per layer). NT is only for full-line
//      streaming data. Scale-prefetch ring kept (neutral, sound margin).

__device__ __forceinline__ unsigned short f32_to_bf16(float f) {
    union { float f; uint32_t u; } v; v.f = f;
    uint32_t u = v.u;
    uint32_t r = (u + 0x7fffu + ((u >> 16) & 1u)) >> 16;   // RNE
    return (unsigned short)r;
}

// raw barrier: execution sync WITHOUT __syncthreads' vmcnt(0)/lgkmcnt(0) drain
__device__ __forceinline__ void barrier_raw() {
    asm volatile("s_barrier" ::: "memory");
}
__device__ __forceinline__ void lgkmwait0() {
    asm volatile("s_waitcnt lgkmcnt(0)" ::: "memory");
}
template <int N> __device__ __forceinline__ void vmwait() {
    if constexpr (N == 0)  asm volatile("s_waitcnt vmcnt(0)"  ::: "memory");
    if constexpr (N == 4)  asm volatile("s_waitcnt vmcnt(4)"  ::: "memory");
    if constexpr (N == 6)  asm volatile("s_waitcnt vmcnt(6)"  ::: "memory");
    if constexpr (N == 10) asm volatile("s_waitcnt vmcnt(10)" ::: "memory");
}

// ---------------------------------------------------------------------------
// W prep, all three layers in ONE launch (saves 2 launch gaps).
//   Wt[m][kk][cb][lane][j] = W[m][ kk*16 + (lane>>5)*8 + j ][ cb*32 + (lane&31) ]
// W0 is padded to KK=4 (h in [40,64) -> 0). fp32 W reads NT (dead after this
// kernel, full-line streaming -> safe NT use).
// ---------------------------------------------------------------------------
__global__ void k_wprep_all(const float* __restrict__ W0, const float* __restrict__ W1,
                            const float* __restrict__ W2,
                            unsigned short* __restrict__ W0t,
                            unsigned short* __restrict__ W1t,
                            unsigned short* __restrict__ W2t) {
    int bi = blockIdx.x;                 // W0: 640 blocks, W1/W2: 1280 each
    const float* W; unsigned short* Wt; int KK, H;
    if (bi < 640)       { W = W0; Wt = W0t; KK = 4; H = 40; }
    else if (bi < 1920) { bi -= 640;  W = W1; Wt = W1t; KK = 8; H = 128; }
    else                { bi -= 1920; W = W2; Wt = W2t; KK = 8; H = 128; }
    int lane = threadIdx.x;
    int cb = bi & 3;
    int mkk = bi >> 2;
    int kk = mkk % KK, m = mkk / KK;
    int l = cb * 32 + (lane & 31);
    int hbase = kk * 16 + (lane >> 5) * 8;
    unsigned short o[8];
#pragma unroll
    for (int j = 0; j < 8; ++j) {
        int h = hbase + j;
        float v = (h < H) ? __builtin_nontemporal_load(&W[((size_t)m * H + h) * LDIM + l]) : 0.f;
        o[j] = f32_to_bf16(v);
    }
    *(short8*)(Wt + (((size_t)(m * KK + kk) * 4 + cb) * 64 + lane) * 8) = *(const short8*)o;
}

// ---------------------------------------------------------------------------
// One layer's K-loop: proven ring-4 / raw-barrier / counted-vmcnt body.
// Operand-swapped: W = A-operand, XK = B-operand -> D[l, row]; per-row scale
// s_m is a per-lane scalar applied in a tiny float2 epilogue.
// KK=4 (L0, UPM=1, gate 6) or KK=8 (L1/L2, UPM=2, gate 10).
//
// R3: P[2][2] is NOT zero-initialized per m (was 64 v_movs in the post-burst
// serial window). kk==0 MFMAs take an opaque loop-invariant zero vector as
// the C operand (D != C is architecturally fine; z0 built via inline asm so
// the compiler can't fold it back into per-m zeroinit).
// ---------------------------------------------------------------------------
template <int KK>
__device__ __forceinline__ void layer_loop(
    const unsigned short* __restrict__ Wt,     // bf16 [MF][KK][4][64][8]
    const float* __restrict__ x, int b,
    int lane, int hf, int r31, int cbg0, int cbg1,
    unsigned short* slabf,                     // &slab[0][0]: 4 slots x 8192 shorts
    bf16x8 (&xk)[2][8], floatx16 (&acc)[2][2])
{
    constexpr int UPM  = KK / 4;               // units per m
    constexpr int NU   = MF * UPM;             // total units (16 KB each)
    constexpr int GATE = (KK == 8) ? 10 : 6;   // = vmem insts per m (uniform)

    auto stage = [&](int uu) {                 // stage unit uu (clamped: same bytes)
        int u = uu < NU ? uu : NU - 1;
        const unsigned short* src = Wt + (size_t)u * 8192;
        const int tid = threadIdx.x;
#pragma unroll
        for (int it = 0; it < 4; ++it) {
            int c = it * 256 + tid;
            __builtin_amdgcn_global_load_lds(
                (const __attribute__((address_space(1))) uint32_t*)(src + (size_t)c * 8),
                (__attribute__((address_space(3))) uint32_t*)(&slabf[(size_t)(u & 3) * 8192 + (size_t)c * 8]),
                16, 0, 0);
        }
    };
    auto ldfrag = [&](int u, int frag, int cb) {
        return __builtin_bit_cast(bf16x8, *(const short8*)(
            &slabf[(size_t)(u & 3) * 8192 + ((size_t)(frag * 4 + cb) * 64 + lane) * 8]));
    };

    acc[0][0] = floatx16{}; acc[0][1] = floatx16{};
    acc[1][0] = floatx16{}; acc[1][1] = floatx16{};

    // opaque zero C-operand: 16 regs, built ONCE per layer, LICM'd across m.
    float z0;
    asm("v_mov_b32 %0, 0" : "=v"(z0));
    floatx16 zc;
#pragma unroll
    for (int i = 0; i < 16; ++i) zc[i] = z0;

    // prologue: fill 3 ring slots; units 0,1 retired before priming.
    // m=0's scale loads issued first so vmwait<4> retires them too.
    vmwait<0>();
    float s0n, s1n;
    {
        const float* sp = x + ((size_t)b * MF + 0) * DDIM + r31;
        s0n = sp[0];
        s1n = sp[32];
    }
    stage(0); stage(1); stage(2);
    vmwait<4>();
    barrier_raw();

    bf16x8 bbuf[2][2];                         // W A-frag register ring
#pragma unroll
    for (int p = 0; p < 2; ++p) {
        bbuf[p][0] = ldfrag(0, p, cbg0);
        bbuf[p][1] = ldfrag(0, p, cbg1);
    }

    float s0v = 0.f, s1v = 0.f;

#pragma unroll 1
    for (int m = 0; m < MF; ++m) {
        floatx16 P[2][2];                      // defined by kk==0 (C = zc)
#pragma unroll
        for (int kk = 0; kk < KK; ++kk) {
            if (kk % 4 == 0) {                 // unit top
                barrier_raw();
                asm volatile("s_setprio 1");
                if (kk == 0) {                 // rotate scale ring; prefetch m+1
                    s0v = s0n; s1v = s1n;
                    const int mn = (m + 1 < MF) ? m + 1 : MF - 1;   // clamped dead load
                    const float* sp = x + ((size_t)b * MF + mn) * DDIM + r31;
                    s0n = sp[0];
                    s1n = sp[32];
                }
                stage(m * UPM + kk / 4 + 3);   // 3 units ahead in the ring
            }
            const int slot = kk & 1;
            P[0][0] = __builtin_amdgcn_mfma_f32_32x32x16_bf16(bbuf[slot][0], xk[0][kk], (kk == 0) ? zc : P[0][0], 0, 0, 0);
            P[1][0] = __builtin_amdgcn_mfma_f32_32x32x16_bf16(bbuf[slot][0], xk[1][kk], (kk == 0) ? zc : P[1][0], 0, 0, 0);
            P[0][1] = __builtin_amdgcn_mfma_f32_32x32x16_bf16(bbuf[slot][1], xk[0][kk], (kk == 0) ? zc : P[0][1], 0, 0, 0);
            P[1][1] = __builtin_amdgcn_mfma_f32_32x32x16_bf16(bbuf[slot][1], xk[1][kk], (kk == 0) ? zc : P[1][1], 0, 0, 0);
            {   // prefetch 2 kk ahead (crosses unit/m boundary; all compile-time)
                const int j  = kk + 2;
                int mm = m + ((j >= KK) ? 1 : 0);
                if (mm > MF - 1) mm = MF - 1;
                const int jj = (j >= KK) ? (j - KK) : j;
                const int u  = mm * UPM + jj / 4;
                bbuf[slot][0] = ldfrag(u, jj % 4, cbg0);
                bbuf[slot][1] = ldfrag(u, jj % 4, cbg1);
            }
            if (kk % 4 == 3) vmwait<GATE>();   // uniform end-of-unit gate
        }
        asm volatile("s_setprio 0");
        // epilogue: acc += s_t * P (float2 -> v_pk_fma_f32)
#pragma unroll
        for (int t = 0; t < 2; ++t) {
            const float sv = (t == 0) ? s0v : s1v;
            floatx2 s2 = {sv, sv};
#pragma unroll
            for (int cbp = 0; cbp < 2; ++cbp) {
                floatx2*       A = (floatx2*)&acc[t][cbp];
                const floatx2* Q = (const floatx2*)&P[t][cbp];
#pragma unroll
                for (int i = 0; i < 8; ++i) A[i] += s2 * Q[i];
            }
        }
    }
}

// ---------------------------------------------------------------------------
// Fused 3-layer CIN kernel. Block = 256 thr = 4 waves (2x2), 2 batches x all
// 128 l's per block; grid 1024 = 2 blocks/CU. X intermediates NEVER touch
// global. ps outputs fused per layer (butterfly shuffle).
//
// R3: ANTI-PHASE STAGGER. The two co-resident blocks per CU run identical
// code and launch together -> in-phase MFMA bursts (both blocks' 64-MFMA
// bursts collide on the shared per-CU matrix pipe, then both idle in
// epilogue/barrier: T~2280 cyc/unit, pipe 45% busy). Dispatch model:
// XCD = blockIdx%8 -> co-resident pairs are (i, i+256), differing in bit 8.
// Odd-bit-8 blocks sleep ~960 cyc at entry so bursts interleave.
// NOTE: (512,4) spilled catastrophically earlier; (256,4) t-split failed R1.
// ---------------------------------------------------------------------------
__global__ __launch_bounds__(256, 2) void k_cin(
    const float* __restrict__ x,               // fp32 [B][MF][DDIM]
    const unsigned short* __restrict__ W0t,    // bf16 [MF][4][4][64][8] (padded)
    const unsigned short* __restrict__ W1t,    // bf16 [MF][8][4][64][8]
    const unsigned short* __restrict__ W2t,    // bf16 [MF][8][4][64][8]
    float* __restrict__ out)                   // fp32 [B][384]
{
    __shared__ unsigned short slab[4][8192];   // 4 x 16 KB W-ring; slots 0-1
                                               // double as the 32 KB X-exchange
    unsigned short* slabf = &slab[0][0];

    // anti-phase stagger: half-a-unit sleep for one block of each CU pair
    if ((blockIdx.x >> 8) & 1) {
        asm volatile("s_sleep 15");            // ~960 cycles
    }

    const int tid  = threadIdx.x;
    const int lane = tid & 63, wave = tid >> 6;
    const int hf   = lane >> 5, r31 = lane & 31;
    const int rowhalf = wave >> 1, colhalf = wave & 1;
    const int b = blockIdx.x * 2 + rowhalf;    // this wave's batch
    const int cbg0 = colhalf * 2, cbg1 = colhalf * 2 + 1;

    bf16x8   xk[2][8];                         // B-operand fragments
    floatx16 acc[2][2];                        // [t(row-tile)][cbp], D[l,row]

    // ---- ps: out[b][OFF+l] = sum over all 64 d (butterfly across lanes) ----
    auto write_ps = [&](int OFF) {
#pragma unroll
        for (int cbp = 0; cbp < 2; ++cbp) {
#pragma unroll
            for (int j = 0; j < 16; ++j) {
                float v = acc[0][cbp][j] + acc[1][cbp][j];
                v += __shfl_xor(v, 16);
                v += __shfl_xor(v, 8);
                v += __shfl_xor(v, 4);
                v += __shfl_xor(v, 2);
                v += __shfl_xor(v, 1);
                if (r31 == 0)
                    out[(size_t)b * 384 + OFF + (colhalf * 2 + cbp) * 32 +
                        (j & 3) + 8 * (j >> 2) + 4 * hf] = v;
            }
        }
    };

    // ---- layer boundary: acc -> LDS (reader frag order) -> xk ----
    // Writer element: row = t*32+r31, l = colhalf*64 + cbp*32 + 8g + 4hf + i
    //   => kk = colhalf*4 + cbp*2 + (g>>1), hfr = g&1, j = 4hf+i
    // Xf addr (shorts): rowhalf*8192 + ((t*8+kk)*64 + hfr*32 + r31)*8 + 4hf
    auto exchange = [&]() {
        vmwait<0>();                           // drain ring staging + ps stores
        barrier_raw();
#pragma unroll
        for (int t = 0; t < 2; ++t)
#pragma unroll
            for (int cbp = 0; cbp < 2; ++cbp)
#pragma unroll
                for (int g = 0; g < 4; ++g) {
                    unsigned short o[4];
#pragma unroll
                    for (int i = 0; i < 4; ++i) o[i] = f32_to_bf16(acc[t][cbp][g * 4 + i]);
                    const int kk  = colhalf * 4 + cbp * 2 + (g >> 1);
                    const int hfr = g & 1;
                    *(short4_t*)(&slabf[(size_t)rowhalf * 8192 +
                        ((size_t)(t * 8 + kk) * 64 + hfr * 32 + r31) * 8 + 4 * hf]) =
                        *(const short4_t*)o;
                }
        lgkmwait0();                           // writes committed to LDS
        barrier_raw();
#pragma unroll
        for (int t = 0; t < 2; ++t)
#pragma unroll
            for (int kk = 0; kk < 8; ++kk)
                xk[t][kk] = __builtin_bit_cast(bf16x8, *(const short8*)(
                    &slabf[(size_t)rowhalf * 8192 + ((size_t)(t * 8 + kk) * 64 + lane) * 8]));
        lgkmwait0();                           // reads in regs before restaging
        barrier_raw();
    };

    // ---- layer 0: xk from original x (KK=4 padded, h<MF else 0) ----
#pragma unroll
    for (int t = 0; t < 2; ++t)
#pragma unroll
        for (int kk = 0; kk < 4; ++kk) {
            unsigned short tmp[8];
#pragma unroll
            for (int j = 0; j < 8; ++j) {
                int h = kk * 16 + hf * 8 + j;
                float v = (h < MF) ? x[((size_t)b * MF + h) * DDIM + t * 32 + r31] : 0.f;
                tmp[j] = f32_to_bf16(v);
            }
            xk[t][kk] = __builtin_bit_cast(bf16x8, *(const short8*)tmp);
        }

    layer_loop<4>(W0t, x, b, lane, hf, r31, cbg0, cbg1, slabf, xk, acc);
    write_ps(0);
    exchange();

    layer_loop<8>(W1t, x, b, lane, hf, r31, cbg0, cbg1, slabf, xk, acc);
    write_ps(128);
    exchange();

    layer_loop<8>(W2t, x, b, lane, hf, r31, cbg0, cbg1, slabf, xk, acc);
    write_ps(256);
}

// ---------------------------------------------------------------------------
extern "C" void kernel_launch(void* const* d_in, const int* in_sizes, int n_in,
                              void* d_out, int out_size, void* d_ws, size_t ws_size,
                              hipStream_t stream) {
    const float* x  = (const float*)d_in[0];
    const float* W0 = (const float*)d_in[1];
    const float* W1 = (const float*)d_in[2];
    const float* W2 = (const float*)d_in[3];
    float* out = (float*)d_out;

    char* ws = (char*)d_ws;
    size_t off = 0;
    auto alloc = [&](size_t bytes) -> void* {
        void* p = ws + off;
        off += (bytes + 255) & ~(size_t)255;
        return p;
    };
    unsigned short* W0t = (unsigned short*)alloc((size_t)MF * 4 * 2048 * 2);   // 0.66 MB
    unsigned short* W1t = (unsigned short*)alloc((size_t)MF * 8 * 2048 * 2);   // 1.31 MB
    unsigned short* W2t = (unsigned short*)alloc((size_t)MF * 8 * 2048 * 2);   // 1.31 MB

    k_wprep_all<<<3200, 64, 0, stream>>>(W0, W1, W2, W0t, W1t, W2t);
    k_cin<<<ROWS / 128, 256, 0, stream>>>(x, W0t, W1t, W2t, out);
}